// Round 1
// baseline (2502.686 us; speedup 1.0000x reference)
//
#include <hip/hip_runtime.h>
#include <hip/hip_bf16.h>
#include <math.h>

#define N_TOK 32768
#define C_DIM 256
#define F_DIM 1024
#define E_NUM 16
#define TILE_R 64
#define F_CHUNK 128

// ---------------- workspace layout (bytes) ----------------
// topk_idx   int[2N]    @ 0          (262144)
// topk_w     float[2N]  @ 262144     (262144)
// token_list int[2N]    @ 524288     (262144)
// weight_lst float[2N]  @ 786432     (262144)
// counts     int[16]    @ 1048576
// fill       int[16]    @ 1048640
// offsets    int[17]    @ 1048704
// tile_pref  int[17]    @ 1048772

__global__ __launch_bounds__(256) void gate_kernel(
    const float* __restrict__ x, const float* __restrict__ gW,
    const float* __restrict__ gb, float* __restrict__ ent_out,
    int* __restrict__ tidx, float* __restrict__ tw, int* __restrict__ counts)
{
    __shared__ float gws[E_NUM * C_DIM];
    __shared__ float gbs[E_NUM];
    __shared__ float went[4];
    int tid = threadIdx.x;

    for (int i = tid; i < E_NUM * C_DIM / 4; i += 256)
        ((float4*)gws)[i] = ((const float4*)gW)[i];
    if (tid < E_NUM) gbs[tid] = gb[tid];
    __syncthreads();

    int n = blockIdx.x * 256 + tid;
    float logit[E_NUM];
    #pragma unroll
    for (int e = 0; e < E_NUM; e++) logit[e] = gbs[e];

    const float4* xr = (const float4*)(x + (size_t)n * C_DIM);
    for (int c4 = 0; c4 < C_DIM / 4; c4++) {
        float4 xv = xr[c4];
        #pragma unroll
        for (int e = 0; e < E_NUM; e++) {
            float4 g = ((const float4*)(gws + e * C_DIM))[c4];
            logit[e] += xv.x * g.x + xv.y * g.y + xv.z * g.z + xv.w * g.w;
        }
    }

    // full softmax entropy
    float m = logit[0];
    #pragma unroll
    for (int e = 1; e < E_NUM; e++) m = fmaxf(m, logit[e]);
    float ex[E_NUM];
    float s = 0.f;
    #pragma unroll
    for (int e = 0; e < E_NUM; e++) { ex[e] = __expf(logit[e] - m); s += ex[e]; }
    float inv = 1.f / s;
    float ent = 0.f;
    #pragma unroll
    for (int e = 0; e < E_NUM; e++) {
        float p = ex[e] * inv;
        ent -= p * logf(p + 1e-8f);
    }

    // top-2 (strict >, first index wins on ties — matches lax.top_k)
    float v0 = -1e30f, v1 = -1e30f;
    int i0 = 0, i1 = 0;
    #pragma unroll
    for (int e = 0; e < E_NUM; e++) {
        float l = logit[e];
        if (l > v0) { v1 = v0; i1 = i0; v0 = l; i0 = e; }
        else if (l > v1) { v1 = l; i1 = e; }
    }
    float w1e = __expf(v1 - v0);
    float z = 1.f + w1e;
    float g0 = 1.f / z, g1 = w1e / z;

    tidx[2 * n]     = i0;
    tidx[2 * n + 1] = i1;
    tw[2 * n]       = g0;
    tw[2 * n + 1]   = g1;
    atomicAdd(&counts[i0], 1);
    atomicAdd(&counts[i1], 1);

    // block-reduce entropy, one atomic per block
    float v = ent;
    for (int off = 32; off > 0; off >>= 1) v += __shfl_down(v, off);
    int wid = tid >> 6, lane = tid & 63;
    if (lane == 0) went[wid] = v;
    __syncthreads();
    if (tid == 0) {
        float ssum = went[0] + went[1] + went[2] + went[3];
        atomicAdd(ent_out, ssum * (1.0f / (float)N_TOK));
    }
}

__global__ void prefix_kernel(const int* __restrict__ counts,
                              int* __restrict__ offs, int* __restrict__ tp)
{
    if (threadIdx.x == 0 && blockIdx.x == 0) {
        int o = 0, t = 0;
        offs[0] = 0; tp[0] = 0;
        for (int e = 0; e < E_NUM; e++) {
            o += counts[e];
            t += (counts[e] + TILE_R - 1) / TILE_R;
            offs[e + 1] = o;
            tp[e + 1] = t;
        }
    }
}

__global__ __launch_bounds__(256) void scatter_kernel(
    const int* __restrict__ tidx, const float* __restrict__ tw,
    const int* __restrict__ offs, int* __restrict__ fill,
    int* __restrict__ tok, float* __restrict__ wgt)
{
    int n = blockIdx.x * 256 + threadIdx.x;
    #pragma unroll
    for (int k = 0; k < 2; k++) {
        int e = tidx[2 * n + k];
        int pos = offs[e] + atomicAdd(&fill[e], 1);
        tok[pos] = n;
        wgt[pos] = tw[2 * n + k];
    }
}

__global__ __launch_bounds__(256, 1) void ffn_kernel(
    const float* __restrict__ x, const float* __restrict__ W1,
    const float* __restrict__ b1, const float* __restrict__ W2,
    const float* __restrict__ b2, const int* __restrict__ tok,
    const float* __restrict__ wgt, const int* __restrict__ offs,
    const int* __restrict__ tp, float* __restrict__ out)
{
    __shared__ float xs[TILE_R * C_DIM];   // 64 KB
    __shared__ float hs[TILE_R * F_CHUNK]; // 32 KB
    __shared__ int   s_tok[TILE_R];
    __shared__ float s_w[TILE_R];

    int b = blockIdx.x;
    int total = tp[E_NUM];
    if (b >= total) return;

    int e = 0, tile_in = 0;
    for (int i = 0; i < E_NUM; i++)
        if (b >= tp[i] && b < tp[i + 1]) { e = i; tile_in = b - tp[i]; }

    int seg_base = offs[e];
    int cnt = offs[e + 1] - seg_base;
    int base = seg_base + tile_in * TILE_R;
    int rows = cnt - tile_in * TILE_R;
    if (rows > TILE_R) rows = TILE_R;

    int tid = threadIdx.x;
    if (tid < TILE_R) {
        int src = (tid < rows) ? base + tid : base;
        s_tok[tid] = tok[src];
        s_w[tid] = (tid < rows) ? wgt[src] : 0.f;
    }
    __syncthreads();

    // stage x tile: thread -> row tid/4, quarter tid%4
    {
        int r = tid >> 2, q = tid & 3;
        const float4* src = (const float4*)(x + (size_t)s_tok[r] * C_DIM + q * 64);
        float4* dst = (float4*)(xs + r * C_DIM + q * 64);
        #pragma unroll
        for (int i = 0; i < 16; i++) dst[i] = src[i];
    }
    __syncthreads();

    int fg = tid & 31;            // f sub-block (phase 1): f0 = fch + 4*fg
    int cg = tid & 31;            // c sub-block (phase 2): c0 = 8*cg
    int r0 = (tid >> 5) * 8;      // row group (both phases)
    int c0 = cg * 8;

    const float* W1e = W1 + (size_t)e * C_DIM * F_DIM;
    const float* W2e = W2 + (size_t)e * F_DIM * C_DIM;

    float acc2[8][8];
    #pragma unroll
    for (int r = 0; r < 8; r++)
        #pragma unroll
        for (int j = 0; j < 8; j++) acc2[r][j] = 0.f;

    for (int fch = 0; fch < F_DIM; fch += F_CHUNK) {
        int f0 = fch + 4 * fg;
        float acc[8][4];
        #pragma unroll
        for (int r = 0; r < 8; r++)
            #pragma unroll
            for (int j = 0; j < 4; j++) acc[r][j] = 0.f;

        for (int c = 0; c < C_DIM; c += 4) {
            float xv[8][4];
            #pragma unroll
            for (int r = 0; r < 8; r++) {
                float4 t = *(const float4*)(xs + (r0 + r) * C_DIM + c);
                xv[r][0] = t.x; xv[r][1] = t.y; xv[r][2] = t.z; xv[r][3] = t.w;
            }
            #pragma unroll
            for (int i = 0; i < 4; i++) {
                float4 wv = *(const float4*)(W1e + (size_t)(c + i) * F_DIM + f0);
                #pragma unroll
                for (int r = 0; r < 8; r++) {
                    acc[r][0] = fmaf(xv[r][i], wv.x, acc[r][0]);
                    acc[r][1] = fmaf(xv[r][i], wv.y, acc[r][1]);
                    acc[r][2] = fmaf(xv[r][i], wv.z, acc[r][2]);
                    acc[r][3] = fmaf(xv[r][i], wv.w, acc[r][3]);
                }
            }
        }

        __syncthreads(); // prev phase-2 done reading hs
        float4 b1v = *(const float4*)(b1 + e * F_DIM + f0);
        #pragma unroll
        for (int r = 0; r < 8; r++) {
            float4 h;
            h.x = fmaxf(acc[r][0] + b1v.x, 0.f);
            h.y = fmaxf(acc[r][1] + b1v.y, 0.f);
            h.z = fmaxf(acc[r][2] + b1v.z, 0.f);
            h.w = fmaxf(acc[r][3] + b1v.w, 0.f);
            *(float4*)(hs + (r0 + r) * F_CHUNK + (f0 - fch)) = h;
        }
        __syncthreads(); // hs ready

        for (int f = 0; f < F_CHUNK; f += 4) {
            float hv[8][4];
            #pragma unroll
            for (int r = 0; r < 8; r++) {
                float4 t = *(const float4*)(hs + (r0 + r) * F_CHUNK + f);
                hv[r][0] = t.x; hv[r][1] = t.y; hv[r][2] = t.z; hv[r][3] = t.w;
            }
            #pragma unroll
            for (int i = 0; i < 4; i++) {
                const float* w2p = W2e + (size_t)(fch + f + i) * C_DIM + c0;
                float4 wa = *(const float4*)w2p;
                float4 wb = *(const float4*)(w2p + 4);
                #pragma unroll
                for (int r = 0; r < 8; r++) {
                    float h = hv[r][i];
                    acc2[r][0] = fmaf(h, wa.x, acc2[r][0]);
                    acc2[r][1] = fmaf(h, wa.y, acc2[r][1]);
                    acc2[r][2] = fmaf(h, wa.z, acc2[r][2]);
                    acc2[r][3] = fmaf(h, wa.w, acc2[r][3]);
                    acc2[r][4] = fmaf(h, wb.x, acc2[r][4]);
                    acc2[r][5] = fmaf(h, wb.y, acc2[r][5]);
                    acc2[r][6] = fmaf(h, wb.z, acc2[r][6]);
                    acc2[r][7] = fmaf(h, wb.w, acc2[r][7]);
                }
            }
        }
    }

    // epilogue: out[token][c] += w * (acc2 + b2)
    float4 b2a = *(const float4*)(b2 + e * C_DIM + c0);
    float4 b2b = *(const float4*)(b2 + e * C_DIM + c0 + 4);
    #pragma unroll
    for (int r = 0; r < 8; r++) {
        int row = r0 + r;
        float w = s_w[row];
        if (w != 0.f) {
            float* orow = out + (size_t)s_tok[row] * C_DIM + c0;
            atomicAdd(&orow[0], w * (acc2[r][0] + b2a.x));
            atomicAdd(&orow[1], w * (acc2[r][1] + b2a.y));
            atomicAdd(&orow[2], w * (acc2[r][2] + b2a.z));
            atomicAdd(&orow[3], w * (acc2[r][3] + b2a.w));
            atomicAdd(&orow[4], w * (acc2[r][4] + b2b.x));
            atomicAdd(&orow[5], w * (acc2[r][5] + b2b.y));
            atomicAdd(&orow[6], w * (acc2[r][6] + b2b.z));
            atomicAdd(&orow[7], w * (acc2[r][7] + b2b.w));
        }
    }
}

extern "C" void kernel_launch(void* const* d_in, const int* in_sizes, int n_in,
                              void* d_out, int out_size, void* d_ws, size_t ws_size,
                              hipStream_t stream)
{
    const float* x   = (const float*)d_in[0];
    const float* gW  = (const float*)d_in[1];
    const float* gb  = (const float*)d_in[2];
    const float* W1  = (const float*)d_in[3];
    const float* b1  = (const float*)d_in[4];
    const float* W2  = (const float*)d_in[5];
    const float* b2  = (const float*)d_in[6];
    float* out = (float*)d_out;

    char* ws = (char*)d_ws;
    int*   topk_idx = (int*)(ws + 0);
    float* topk_w   = (float*)(ws + 262144);
    int*   tok      = (int*)(ws + 524288);
    float* wgt      = (float*)(ws + 786432);
    int*   counts   = (int*)(ws + 1048576);
    int*   fill     = (int*)(ws + 1048640);
    int*   offs     = (int*)(ws + 1048704);
    int*   tp       = (int*)(ws + 1048772);

    // zero output (atomicAdd target) + entropy slot + counters
    hipMemsetAsync(d_out, 0, (size_t)(N_TOK * C_DIM + 1) * sizeof(float), stream);
    hipMemsetAsync(counts, 0, 2 * E_NUM * sizeof(int), stream); // counts + fill

    float* ent_out = out + (size_t)N_TOK * C_DIM;

    gate_kernel<<<N_TOK / 256, 256, 0, stream>>>(x, gW, gb, ent_out,
                                                 topk_idx, topk_w, counts);
    prefix_kernel<<<1, 64, 0, stream>>>(counts, offs, tp);
    scatter_kernel<<<N_TOK / 256, 256, 0, stream>>>(topk_idx, topk_w, offs,
                                                    fill, tok, wgt);
    ffn_kernel<<<1040, 256, 0, stream>>>(x, W1, b1, W2, b2, tok, wgt,
                                         offs, tp, out);
}

// Round 2
// 593.637 us; speedup vs baseline: 4.2159x; 4.2159x over previous
//
#include <hip/hip_runtime.h>
#include <hip/hip_bf16.h>
#include <math.h>

#define N_TOK 32768
#define C_DIM 256
#define F_DIM 1024
#define E_NUM 16
#define TILE_R 64
#define FCH 64
#define NCH 16

typedef unsigned short u16;
typedef unsigned int u32;
typedef __attribute__((ext_vector_type(8))) u16 u16x8;
typedef __attribute__((ext_vector_type(8))) short bf16x8;
typedef __attribute__((ext_vector_type(4))) float f32x4;

#define AS1 __attribute__((address_space(1)))
#define AS3 __attribute__((address_space(3)))

// async global->LDS, 16B per lane; LDS dest = wave-uniform base + lane*16
__device__ __forceinline__ void gload16(const void* g, void* lds) {
    __builtin_amdgcn_global_load_lds((const AS1 u32*)(uintptr_t)g,
                                     (AS3 u32*)(u32)(uintptr_t)lds, 16, 0, 0);
}

__device__ __forceinline__ u16 f2bf(float f) {
    union { float f; u32 u; } v; v.f = f;
    u32 r = v.u + 0x7fffu + ((v.u >> 16) & 1u);   // RNE
    return (u16)(r >> 16);
}

// ---------------- workspace layout (bytes) ----------------
// 0        topk_idx int[2N]
// 262144   topk_w   f32[2N]
// 524288   tok      int[2N]
// 786432   wgt      f32[2N]
// 1048576  pairpos  int[2N]
// 1310720  counts[16] fill[16] offs[17] tp[17]
// 2097152  xb   bf16[N][C]        (16.8 MB)
// 18874368 w1t  bf16[E][F][C]     (8.4 MB)
// 27262976 w2t  bf16[E][C][F]     (8.4 MB)
// 35651584 ybuf f32[2N][C]        (67.1 MB, MODE 0 only)

__global__ __launch_bounds__(256) void gate_kernel(
    const float* __restrict__ x, const float* __restrict__ gW,
    const float* __restrict__ gb, float* __restrict__ ent_out,
    int* __restrict__ tidx, float* __restrict__ tw, int* __restrict__ counts)
{
    __shared__ float gws[E_NUM * C_DIM];
    __shared__ float gbs[E_NUM];
    __shared__ float went[4];
    int tid = threadIdx.x;

    for (int i = tid; i < E_NUM * C_DIM / 4; i += 256)
        ((float4*)gws)[i] = ((const float4*)gW)[i];
    if (tid < E_NUM) gbs[tid] = gb[tid];
    __syncthreads();

    int n = blockIdx.x * 256 + tid;
    float logit[E_NUM];
    #pragma unroll
    for (int e = 0; e < E_NUM; e++) logit[e] = gbs[e];

    const float4* xr = (const float4*)(x + (size_t)n * C_DIM);
    for (int c4 = 0; c4 < C_DIM / 4; c4++) {
        float4 xv = xr[c4];
        #pragma unroll
        for (int e = 0; e < E_NUM; e++) {
            float4 g = ((const float4*)(gws + e * C_DIM))[c4];
            logit[e] += xv.x * g.x + xv.y * g.y + xv.z * g.z + xv.w * g.w;
        }
    }

    float m = logit[0];
    #pragma unroll
    for (int e = 1; e < E_NUM; e++) m = fmaxf(m, logit[e]);
    float ex[E_NUM];
    float s = 0.f;
    #pragma unroll
    for (int e = 0; e < E_NUM; e++) { ex[e] = __expf(logit[e] - m); s += ex[e]; }
    float inv = 1.f / s;
    float ent = 0.f;
    #pragma unroll
    for (int e = 0; e < E_NUM; e++) {
        float p = ex[e] * inv;
        ent -= p * logf(p + 1e-8f);
    }

    float v0 = -1e30f, v1 = -1e30f;
    int i0 = 0, i1 = 0;
    #pragma unroll
    for (int e = 0; e < E_NUM; e++) {
        float l = logit[e];
        if (l > v0) { v1 = v0; i1 = i0; v0 = l; i0 = e; }
        else if (l > v1) { v1 = l; i1 = e; }
    }
    float w1e = __expf(v1 - v0);
    float z = 1.f + w1e;

    tidx[2 * n]     = i0;
    tidx[2 * n + 1] = i1;
    tw[2 * n]       = 1.f / z;
    tw[2 * n + 1]   = w1e / z;
    atomicAdd(&counts[i0], 1);
    atomicAdd(&counts[i1], 1);

    float v = ent;
    for (int off = 32; off > 0; off >>= 1) v += __shfl_down(v, off);
    int wid = tid >> 6, lane = tid & 63;
    if (lane == 0) went[wid] = v;
    __syncthreads();
    if (tid == 0) {
        float ssum = went[0] + went[1] + went[2] + went[3];
        atomicAdd(ent_out, ssum * (1.0f / (float)N_TOK));
    }
}

__global__ void prefix_kernel(const int* __restrict__ counts,
                              int* __restrict__ offs, int* __restrict__ tp)
{
    if (threadIdx.x == 0 && blockIdx.x == 0) {
        int o = 0, t = 0;
        offs[0] = 0; tp[0] = 0;
        for (int e = 0; e < E_NUM; e++) {
            o += counts[e];
            t += (counts[e] + TILE_R - 1) / TILE_R;
            offs[e + 1] = o;
            tp[e + 1] = t;
        }
    }
}

__global__ __launch_bounds__(256) void scatter_kernel(
    const int* __restrict__ tidx, const float* __restrict__ tw,
    const int* __restrict__ offs, int* __restrict__ fill,
    int* __restrict__ tok, float* __restrict__ wgt, int* __restrict__ pairpos)
{
    int n = blockIdx.x * 256 + threadIdx.x;
    #pragma unroll
    for (int k = 0; k < 2; k++) {
        int e = tidx[2 * n + k];
        int pos = offs[e] + atomicAdd(&fill[e], 1);
        tok[pos] = n;
        wgt[pos] = tw[2 * n + k];
        pairpos[2 * n + k] = pos;
    }
}

// x f32 -> bf16, same layout
__global__ __launch_bounds__(256) void cvt_x_kernel(
    const float* __restrict__ x, u16* __restrict__ xb)
{
    int i = blockIdx.x * 256 + threadIdx.x;
    const float4* p = (const float4*)(x + (size_t)i * 8);
    float4 a = p[0], b = p[1];
    u16x8 o;
    o[0] = f2bf(a.x); o[1] = f2bf(a.y); o[2] = f2bf(a.z); o[3] = f2bf(a.w);
    o[4] = f2bf(b.x); o[5] = f2bf(b.y); o[6] = f2bf(b.z); o[7] = f2bf(b.w);
    *(u16x8*)(xb + (size_t)i * 8) = o;
}

// per-expert transpose+convert: src f32 [R][Cc] -> dst bf16 [Cc][R]
__global__ __launch_bounds__(256) void tcvt_kernel(
    const float* __restrict__ src, u16* __restrict__ dst, int R, int Cc)
{
    __shared__ float t[64][65];
    int e = blockIdx.x;
    int r0 = blockIdx.y << 6, c0 = blockIdx.z << 6;
    const float* s = src + (size_t)e * R * Cc;
    u16* d = dst + (size_t)e * R * Cc;
    int tid = threadIdx.x;
    int rr = tid >> 4, cc = (tid & 15) << 2;
    #pragma unroll
    for (int it = 0; it < 4; it++) {
        float4 v = *(const float4*)(s + (size_t)(r0 + rr + it * 16) * Cc + c0 + cc);
        t[rr + it * 16][cc]     = v.x;
        t[rr + it * 16][cc + 1] = v.y;
        t[rr + it * 16][cc + 2] = v.z;
        t[rr + it * 16][cc + 3] = v.w;
    }
    __syncthreads();
    int cr = tid >> 3, rq = (tid & 7) << 3;
    #pragma unroll
    for (int it = 0; it < 2; it++) {
        int c = cr + it * 32;
        u16x8 o;
        #pragma unroll
        for (int j = 0; j < 8; j++) o[j] = f2bf(t[rq + j][c]);
        *(u16x8*)(d + (size_t)(c0 + c) * R + r0 + rq) = o;
    }
}

// MODE 0: write f32 partials to ybuf (combine kernel finishes)
// MODE 1: atomicAdd weighted result directly into out (ws too small for ybuf)
template <int MODE>
__global__ __launch_bounds__(256, 1) void ffn_mfma(
    const u16* __restrict__ xb, const u16* __restrict__ w1t,
    const u16* __restrict__ w2t, const float* __restrict__ b1,
    const float* __restrict__ b2, const int* __restrict__ tok,
    const float* __restrict__ wgt, const int* __restrict__ offs,
    const int* __restrict__ tp, float* __restrict__ ybuf,
    float* __restrict__ out)
{
    __shared__ u16 xs[TILE_R * 256];   // [m][c]  swizzled, 32 KB
    __shared__ u16 w1s[FCH * 256];     // [f][c]  swizzled, 32 KB
    __shared__ u16 w2s[256 * FCH];     // [c][f]  swizzled, 32 KB
    __shared__ u16 hs[TILE_R * FCH];   // [m][f]  swizzled,  8 KB
    __shared__ int s_tok[TILE_R];
    __shared__ float s_w[TILE_R];

    int b = blockIdx.x;
    if (b >= tp[E_NUM]) return;
    int e = 0;
    while (b >= tp[e + 1]) e++;
    int tile_in = b - tp[e];
    int base = offs[e] + (tile_in << 6);
    int rows = offs[e + 1] - base; if (rows > TILE_R) rows = TILE_R;

    int tid = threadIdx.x;
    int lane = tid & 63, wid = tid >> 6;
    if (tid < TILE_R) {
        int src = (tid < rows) ? base + tid : base;
        s_tok[tid] = tok[src];
        s_w[tid] = (tid < rows) ? wgt[src] : 0.f;
    }
    __syncthreads();

    const u16* w1e = w1t + (size_t)e * (F_DIM * C_DIM);  // [F][C]
    const u16* w2e = w2t + (size_t)e * (C_DIM * F_DIM);  // [C][F]
    const float* b1e = b1 + e * F_DIM;
    const float* b2e = b2 + e * C_DIM;

    int lofs_base = (wid << 10) + (lane << 4);

    // stage x tile (gathered rows) + W1 chunk 0
    #pragma unroll
    for (int i = 0; i < 8; i++) {
        int lofs = (i << 12) + lofs_base;
        int row = lofs >> 9;
        int sc = ((lofs >> 4) & 31) ^ (row & 7);
        gload16(xb + ((size_t)s_tok[row] << 8) + (sc << 3),
                (char*)xs + (i << 12) + (wid << 10));
    }
    #pragma unroll
    for (int i = 0; i < 8; i++) {
        int lofs = (i << 12) + lofs_base;
        int row = lofs >> 9;
        int sc = ((lofs >> 4) & 31) ^ (row & 7);
        gload16(w1e + ((size_t)row << 8) + (sc << 3),
                (char*)w1s + (i << 12) + (wid << 10));
    }
    __syncthreads();

    int lrow = lane & 15;
    int kb = (lane >> 4) << 4;          // k-group byte offset
    int sw = (lrow & 7) << 4;           // frag-read swizzle (row&7 == lrow&7)
    int wr = wid >> 1, wc = wid & 1;
    int am0 = (wr << 5) + lrow;         // A row (tile 0); +16 for tile 1
    int bf0 = (wc << 5) + lrow;         // W1 row (tile 0)
    int mo0 = (wr << 5) + ((lane >> 4) << 2);  // D row base

    f32x4 acc2[2][8];
    #pragma unroll
    for (int mi = 0; mi < 2; mi++)
        #pragma unroll
        for (int ni = 0; ni < 8; ni++)
            acc2[mi][ni] = (f32x4){0.f, 0.f, 0.f, 0.f};

    for (int ch = 0; ch < NCH; ch++) {
        // stage W2 chunk (overlaps phase 1; drained at mid sync)
        #pragma unroll
        for (int i = 0; i < 8; i++) {
            int lofs = (i << 12) + lofs_base;
            int row = lofs >> 7;
            int sc = ((lofs >> 4) & 7) ^ (row & 7);
            gload16(w2e + ((size_t)row << 10) + (ch << 6) + (sc << 3),
                    (char*)w2s + (i << 12) + (wid << 10));
        }

        // ---- phase 1: H = relu(X @ W1^T + b1) for this F-chunk ----
        f32x4 acc1[2][2];
        #pragma unroll
        for (int mi = 0; mi < 2; mi++)
            #pragma unroll
            for (int ni = 0; ni < 2; ni++)
                acc1[mi][ni] = (f32x4){0.f, 0.f, 0.f, 0.f};

        #pragma unroll
        for (int ks = 0; ks < 8; ks++) {
            int k2 = (ks << 6) + kb;
            bf16x8 a0 = *(const bf16x8*)((const char*)xs + (am0 << 9) + (k2 ^ sw));
            bf16x8 a1 = *(const bf16x8*)((const char*)xs + ((am0 + 16) << 9) + (k2 ^ sw));
            bf16x8 b0 = *(const bf16x8*)((const char*)w1s + (bf0 << 9) + (k2 ^ sw));
            bf16x8 b1f = *(const bf16x8*)((const char*)w1s + ((bf0 + 16) << 9) + (k2 ^ sw));
            acc1[0][0] = __builtin_amdgcn_mfma_f32_16x16x32_bf16(a0, b0, acc1[0][0], 0, 0, 0);
            acc1[0][1] = __builtin_amdgcn_mfma_f32_16x16x32_bf16(a0, b1f, acc1[0][1], 0, 0, 0);
            acc1[1][0] = __builtin_amdgcn_mfma_f32_16x16x32_bf16(a1, b0, acc1[1][0], 0, 0, 0);
            acc1[1][1] = __builtin_amdgcn_mfma_f32_16x16x32_bf16(a1, b1f, acc1[1][1], 0, 0, 0);
        }

        // relu + b1 -> hs (bf16, swizzled)
        #pragma unroll
        for (int ni = 0; ni < 2; ni++) {
            int fl = (wc << 5) + (ni << 4) + lrow;
            float b1v = b1e[(ch << 6) + fl];
            #pragma unroll
            for (int mi = 0; mi < 2; mi++) {
                #pragma unroll
                for (int r = 0; r < 4; r++) {
                    int m = mo0 + (mi << 4) + r;
                    float h = fmaxf(acc1[mi][ni][r] + b1v, 0.f);
                    *(u16*)((char*)hs + (m << 7) + ((fl << 1) ^ ((m & 7) << 4))) = f2bf(h);
                }
            }
        }
        __syncthreads();   // hs ready + w2s arrived

        // prefetch next W1 chunk (overlaps phase 2; drained at end sync)
        if (ch + 1 < NCH) {
            #pragma unroll
            for (int i = 0; i < 8; i++) {
                int lofs = (i << 12) + lofs_base;
                int row = lofs >> 9;
                int sc = ((lofs >> 4) & 31) ^ (row & 7);
                gload16(w1e + ((size_t)((ch + 1) * 64 + row) << 8) + (sc << 3),
                        (char*)w1s + (i << 12) + (wid << 10));
            }
        }

        // ---- phase 2: acc2 += H @ W2^T ----
        #pragma unroll
        for (int ks = 0; ks < 2; ks++) {
            int k2 = (ks << 6) + kb;
            bf16x8 ha0 = *(const bf16x8*)((const char*)hs + (am0 << 7) + (k2 ^ sw));
            bf16x8 ha1 = *(const bf16x8*)((const char*)hs + ((am0 + 16) << 7) + (k2 ^ sw));
            #pragma unroll
            for (int ni = 0; ni < 8; ni++) {
                bf16x8 bb = *(const bf16x8*)((const char*)w2s +
                              (((wc << 7) + (ni << 4) + lrow) << 7) + (k2 ^ sw));
                acc2[0][ni] = __builtin_amdgcn_mfma_f32_16x16x32_bf16(ha0, bb, acc2[0][ni], 0, 0, 0);
                acc2[1][ni] = __builtin_amdgcn_mfma_f32_16x16x32_bf16(ha1, bb, acc2[1][ni], 0, 0, 0);
            }
        }
        __syncthreads();   // w2s/hs free for next iter; w1s(ch+1) drained
    }

    if (MODE == 0) {
        #pragma unroll
        for (int mi = 0; mi < 2; mi++) {
            #pragma unroll
            for (int r = 0; r < 4; r++) {
                int m = mo0 + (mi << 4) + r;
                if (m < rows) {
                    float* yr = ybuf + ((size_t)(base + m) << 8) + (wc << 7) + lrow;
                    #pragma unroll
                    for (int ni = 0; ni < 8; ni++) yr[ni << 4] = acc2[mi][ni][r];
                }
            }
        }
    } else {
        #pragma unroll
        for (int mi = 0; mi < 2; mi++) {
            #pragma unroll
            for (int r = 0; r < 4; r++) {
                int m = mo0 + (mi << 4) + r;
                if (m < rows) {
                    float w = s_w[m];
                    float* orow = out + ((size_t)s_tok[m] << 8) + (wc << 7) + lrow;
                    #pragma unroll
                    for (int ni = 0; ni < 8; ni++) {
                        float v = acc2[mi][ni][r] + b2e[(wc << 7) + (ni << 4) + lrow];
                        atomicAdd(&orow[ni << 4], w * v);
                    }
                }
            }
        }
    }
}

__global__ __launch_bounds__(256) void combine_kernel(
    const float* __restrict__ ybuf, const int* __restrict__ tidx,
    const float* __restrict__ tw, const int* __restrict__ pairpos,
    const float* __restrict__ b2, float* __restrict__ out)
{
    int idx = blockIdx.x * 256 + threadIdx.x;
    int n = idx >> 6;
    int q = (idx & 63) << 2;
    int e0 = tidx[2 * n], e1 = tidx[2 * n + 1];
    float w0 = tw[2 * n], w1 = tw[2 * n + 1];
    int p0 = pairpos[2 * n], p1 = pairpos[2 * n + 1];
    float4 y0 = *(const float4*)(ybuf + ((size_t)p0 << 8) + q);
    float4 y1 = *(const float4*)(ybuf + ((size_t)p1 << 8) + q);
    float4 c0 = *(const float4*)(b2 + (e0 << 8) + q);
    float4 c1 = *(const float4*)(b2 + (e1 << 8) + q);
    float4 o;
    o.x = w0 * (y0.x + c0.x) + w1 * (y1.x + c1.x);
    o.y = w0 * (y0.y + c0.y) + w1 * (y1.y + c1.y);
    o.z = w0 * (y0.z + c0.z) + w1 * (y1.z + c1.z);
    o.w = w0 * (y0.w + c0.w) + w1 * (y1.w + c1.w);
    *(float4*)(out + ((size_t)n << 8) + q) = o;
}

extern "C" void kernel_launch(void* const* d_in, const int* in_sizes, int n_in,
                              void* d_out, int out_size, void* d_ws, size_t ws_size,
                              hipStream_t stream)
{
    const float* x   = (const float*)d_in[0];
    const float* gW  = (const float*)d_in[1];
    const float* gb  = (const float*)d_in[2];
    const float* W1  = (const float*)d_in[3];
    const float* b1  = (const float*)d_in[4];
    const float* W2  = (const float*)d_in[5];
    const float* b2  = (const float*)d_in[6];
    float* out = (float*)d_out;

    char* ws = (char*)d_ws;
    int*   topk_idx = (int*)(ws + 0);
    float* topk_w   = (float*)(ws + 262144);
    int*   tok      = (int*)(ws + 524288);
    float* wgt      = (float*)(ws + 786432);
    int*   pairpos  = (int*)(ws + 1048576);
    int*   counts   = (int*)(ws + 1310720);
    int*   fill     = (int*)(ws + 1310784);
    int*   offs     = (int*)(ws + 1310848);
    int*   tp       = (int*)(ws + 1310916);

    const size_t XB_OFF  = 2097152;
    const size_t W1T_OFF = 18874368;
    const size_t W2T_OFF = 27262976;
    const size_t Y_OFF   = 35651584;
    const size_t WS_FULL = Y_OFF + (size_t)2 * N_TOK * C_DIM * 4;  // 102760448

    u16* xb  = (u16*)(ws + XB_OFF);
    u16* w1t = (u16*)(ws + W1T_OFF);
    u16* w2t = (u16*)(ws + W2T_OFF);
    float* ybuf = (float*)(ws + Y_OFF);

    int mode = (ws_size >= WS_FULL) ? 0 : 1;

    hipMemsetAsync(d_out, 0, (size_t)(N_TOK * C_DIM + 1) * sizeof(float), stream);
    hipMemsetAsync(counts, 0, 2 * E_NUM * sizeof(int), stream);

    float* ent_out = out + (size_t)N_TOK * C_DIM;

    gate_kernel<<<N_TOK / 256, 256, 0, stream>>>(x, gW, gb, ent_out,
                                                 topk_idx, topk_w, counts);
    prefix_kernel<<<1, 64, 0, stream>>>(counts, offs, tp);
    scatter_kernel<<<N_TOK / 256, 256, 0, stream>>>(topk_idx, topk_w, offs,
                                                    fill, tok, wgt, pairpos);
    cvt_x_kernel<<<N_TOK * C_DIM / (8 * 256), 256, 0, stream>>>(x, xb);
    tcvt_kernel<<<dim3(E_NUM, C_DIM / 64, F_DIM / 64), 256, 0, stream>>>(W1, w1t, C_DIM, F_DIM);
    tcvt_kernel<<<dim3(E_NUM, F_DIM / 64, C_DIM / 64), 256, 0, stream>>>(W2, w2t, F_DIM, C_DIM);

    if (mode == 0) {
        ffn_mfma<0><<<1040, 256, 0, stream>>>(xb, w1t, w2t, b1, b2, tok, wgt,
                                              offs, tp, ybuf, out);
        combine_kernel<<<N_TOK * 64 / 256, 256, 0, stream>>>(ybuf, topk_idx,
                                                             topk_w, pairpos, b2, out);
    } else {
        ffn_mfma<1><<<1040, 256, 0, stream>>>(xb, w1t, w2t, b1, b2, tok, wgt,
                                              offs, tp, ybuf, out);
    }
}